// Round 5
// baseline (595.087 us; speedup 1.0000x reference)
//
#include <hip/hip_runtime.h>
#include <stdint.h>

// Fixed problem shape: outputs [8,16,384,384] fp32
#define B_ 8
#define D_ 16
#define H_ 384
#define W_ 384
constexpr int HW   = H_ * W_;     // 147456
constexpr int DHW  = D_ * HW;     // 2359296
constexpr int NCOL = B_ * HW;     // 1179648 columns
constexpr unsigned NRUN = (unsigned)NCOL * 8u;  // run-id space: column*8 + run_idx

constexpr float T_LOW  = 0.8f;
constexpr float T_HIGH = 0.92f;
constexpr unsigned DUST_MIN = 20u;

constexpr int NBLK_COL  = NCOL / 256;   // 4608  (1 col/thread kernels)
constexpr int NBLK_QUAD = NCOL / 1024;  // 1152  (4 cols/thread kernels)

// ---------- global union-find over z-run ids ----------
// parent[] : value < NRUN -> parent pointer; value >= NRUN -> root,
// aggregated count = 0xFFFFFFFF - value (init 0xFFFFFFFF => root, count 0).
__device__ __forceinline__ unsigned gfind(const unsigned* A, unsigned x) {
    unsigned p = A[x];
    while (p < NRUN) { x = p; p = A[x]; }
    return x;
}

__device__ __forceinline__ unsigned groot_val(const unsigned* A, unsigned x) {
    unsigned p = A[x];
    while (p < NRUN) { x = p; p = A[x]; }
    return p;   // root's value; count = 0xFFFFFFFF - p
}

__device__ __forceinline__ void gunite(unsigned* A, unsigned a, unsigned b) {
    for (;;) {
        a = gfind(A, a);
        b = gfind(A, b);
        if (a == b) return;
        unsigned lo = a < b ? a : b;
        unsigned hi = a < b ? b : a;
        unsigned old = atomicMin(&A[hi], lo);
        if (old >= NRUN) return;
        a = lo; b = old;
    }
}

// run index containing set bit p of mask m
__device__ __forceinline__ int runidx(unsigned m, int p) {
    unsigned starts = m & ~(m << 1);
    return __popc(starts & ((2u << p) - 1u)) - 1;
}

__device__ __forceinline__ void unite_overlaps(unsigned* parent, int cA, unsigned mA,
                                               int cB, unsigned mB) {
    unsigned ov = mA & mB;
    while (ov) {
        int p = __ffs(ov) - 1;
        gunite(parent, (unsigned)cA * 8u + runidx(mA, p),
                       (unsigned)cB * 8u + runidx(mB, p));
        ov &= ov + (1u << p);   // clear this contiguous overlap segment
    }
}

// XCD-affine swizzle: batch = blockIdx.x & 7. Workgroups round-robin across the
// 8 XCDs, so each batch's parent/cols slice stays in ONE XCD's 4 MB L2.
// Pure locality heuristic: correct under any dispatch mapping.

// ---------------- kernels ----------------

// x -> packed weak|strong column masks (4 cols/thread, float4); init parent1
__global__ __launch_bounds__(256) void k_cols(const float* __restrict__ x,
                                              unsigned* __restrict__ cols,
                                              unsigned* __restrict__ parent1) {
    int b = blockIdx.x & 7;
    int q = (blockIdx.x >> 3) * 256 + threadIdx.x;   // 0..HW/4-1
    int p0 = q * 4;
    const float* xp = x + (size_t)b * DHW + p0;
    unsigned wk0 = 0, wk1 = 0, wk2 = 0, wk3 = 0;
    unsigned st0 = 0, st1 = 0, st2 = 0, st3 = 0;
    #pragma unroll
    for (int z = 0; z < D_; ++z) {
        float4 v = *(const float4*)(xp + (size_t)z * HW);
        wk0 |= (v.x >= T_LOW  ? 1u : 0u) << z;  st0 |= (v.x >= T_HIGH ? 1u : 0u) << z;
        wk1 |= (v.y >= T_LOW  ? 1u : 0u) << z;  st1 |= (v.y >= T_HIGH ? 1u : 0u) << z;
        wk2 |= (v.z >= T_LOW  ? 1u : 0u) << z;  st2 |= (v.z >= T_HIGH ? 1u : 0u) << z;
        wk3 |= (v.w >= T_LOW  ? 1u : 0u) << z;  st3 |= (v.w >= T_HIGH ? 1u : 0u) << z;
    }
    int c0 = b * HW + p0;
    *(uint4*)(cols + c0) = make_uint4(wk0 | (st0 << 16), wk1 | (st1 << 16),
                                      wk2 | (st2 << 16), wk3 | (st3 << 16));
    // lazy parent init: 32 entries (4 cols x 8 runs) = 128 B, coalesced
    uint4* pp = (uint4*)(parent1 + (size_t)c0 * 8u);
    uint4 ff = make_uint4(~0u, ~0u, ~0u, ~0u);
    #pragma unroll
    for (int i = 0; i < 8; ++i) pp[i] = ff;
}

// unions between overlapping weak runs of (c,c+1) and (c,c+W)
__global__ __launch_bounds__(256) void k_union1(const unsigned* __restrict__ cols,
                                                unsigned* parent1) {
    int b = blockIdx.x & 7;
    int t = (blockIdx.x >> 3) * 256 + threadIdx.x;   // 0..HW-1
    int c = b * HW + t;
    unsigned mA = cols[c] & 0xFFFFu;
    if (!mA) return;
    int w = t % W_, h = t / W_;
    if (w < W_ - 1) {
        unsigned mB = cols[c + 1] & 0xFFFFu;
        if (mA & mB) unite_overlaps(parent1, c, mA, c + 1, mB);
    }
    if (h < H_ - 1) {
        unsigned mB = cols[c + W_] & 0xFFFFu;
        if (mA & mB) unite_overlaps(parent1, c, mA, c + W_, mB);
    }
}

// aggregate per-run strong counts into component roots
__global__ __launch_bounds__(256) void k_agg1(const unsigned* __restrict__ cols,
                                              unsigned* parent1) {
    int b = blockIdx.x & 7;
    int t = (blockIdx.x >> 3) * 256 + threadIdx.x;
    int c = b * HW + t;
    unsigned cc = cols[c];
    unsigned wk = cc & 0xFFFFu, st = cc >> 16;
    if (!st) return;
    unsigned rem = wk; int idx = 0;
    while (rem) {
        int p = __ffs(rem) - 1;
        unsigned tt = rem >> p;
        int len = __ffs(~tt) - 1;
        unsigned runmask = ((1u << len) - 1u) << p;
        unsigned sc = (unsigned)__popc(runmask & st);
        if (sc) {
            unsigned r = gfind(parent1, (unsigned)c * 8u + idx);
            atomicSub(&parent1[r], sc);
        }
        rem &= ~runmask; ++idx;
    }
}

// hysteresis + z-closing -> closed masks; init parent2
__global__ __launch_bounds__(256) void k_close(const unsigned* __restrict__ cols,
                                               const unsigned* __restrict__ parent1,
                                               unsigned short* __restrict__ closed,
                                               unsigned* __restrict__ parent2) {
    int b = blockIdx.x & 7;
    int t = (blockIdx.x >> 3) * 256 + threadIdx.x;
    int c = b * HW + t;
    unsigned wk = cols[c] & 0xFFFFu;
    unsigned m = 0;
    unsigned rem = wk; int idx = 0;
    while (rem) {
        int p = __ffs(rem) - 1;
        unsigned tt = rem >> p;
        int len = __ffs(~tt) - 1;
        unsigned runmask = ((1u << len) - 1u) << p;
        if (groot_val(parent1, (unsigned)c * 8u + idx) != 0xFFFFFFFFu)  // strong count > 0
            m |= runmask;
        rem &= ~runmask; ++idx;
    }
    // z-closing: dilate (OOB = background), erode (OOB = foreground)
    unsigned dil = (m | (m << 1) | (m >> 1)) & 0xFFFFu;
    unsigned ero = dil & ((dil << 1) | 1u) & ((dil >> 1) | 0x8000u);
    closed[c] = (unsigned short)ero;
    // lazy parent2 init: 8 entries / column, 32 B, coalesced
    uint4* pp = (uint4*)(parent2 + (size_t)c * 8u);
    uint4 ff = make_uint4(~0u, ~0u, ~0u, ~0u);
    pp[0] = ff; pp[1] = ff;
}

// unions between overlapping closed runs
__global__ __launch_bounds__(256) void k_union2(const unsigned short* __restrict__ closed,
                                                unsigned* parent2) {
    int b = blockIdx.x & 7;
    int t = (blockIdx.x >> 3) * 256 + threadIdx.x;
    int c = b * HW + t;
    unsigned mA = closed[c];
    if (!mA) return;
    int w = t % W_, h = t / W_;
    if (w < W_ - 1) {
        unsigned mB = closed[c + 1];
        if (mA & mB) unite_overlaps(parent2, c, mA, c + 1, mB);
    }
    if (h < H_ - 1) {
        unsigned mB = closed[c + W_];
        if (mA & mB) unite_overlaps(parent2, c, mA, c + W_, mB);
    }
}

// aggregate per-run voxel counts into component roots
__global__ __launch_bounds__(256) void k_agg2(const unsigned short* __restrict__ closed,
                                              unsigned* parent2) {
    int b = blockIdx.x & 7;
    int t = (blockIdx.x >> 3) * 256 + threadIdx.x;
    int c = b * HW + t;
    unsigned fg = closed[c];
    if (!fg) return;
    unsigned rem = fg; int idx = 0;
    while (rem) {
        int p = __ffs(rem) - 1;
        unsigned tt = rem >> p;
        int len = __ffs(~tt) - 1;
        unsigned runmask = ((1u << len) - 1u) << p;
        unsigned r = gfind(parent2, (unsigned)c * 8u + idx);
        atomicSub(&parent2[r], (unsigned)__popc(runmask));
        rem &= ~runmask; ++idx;
    }
}

// keep components with size >= DUST_MIN; write 0/1 float (4 cols/thread, float4)
__global__ __launch_bounds__(256) void k_out(const unsigned short* __restrict__ closed,
                                             const unsigned* __restrict__ parent2,
                                             float* __restrict__ out) {
    int b = blockIdx.x & 7;
    int q = (blockIdx.x >> 3) * 256 + threadIdx.x;
    int p0 = q * 4;
    int c0 = b * HW + p0;
    unsigned keep[4];
    #pragma unroll
    for (int j = 0; j < 4; ++j) {
        int c = c0 + j;
        unsigned fg = closed[c];
        unsigned k = 0;
        unsigned rem = fg; int idx = 0;
        while (rem) {
            int p = __ffs(rem) - 1;
            unsigned tt = rem >> p;
            int len = __ffs(~tt) - 1;
            unsigned runmask = ((1u << len) - 1u) << p;
            if (0xFFFFFFFFu - groot_val(parent2, (unsigned)c * 8u + idx) >= DUST_MIN)
                k |= runmask;
            rem &= ~runmask; ++idx;
        }
        keep[j] = k;
    }
    float* op = out + (size_t)b * DHW + p0;
    #pragma unroll
    for (int z = 0; z < D_; ++z) {
        *(float4*)(op + (size_t)z * HW) =
            make_float4((keep[0] >> z) & 1u ? 1.0f : 0.0f,
                        (keep[1] >> z) & 1u ? 1.0f : 0.0f,
                        (keep[2] >> z) & 1u ? 1.0f : 0.0f,
                        (keep[3] >> z) & 1u ? 1.0f : 0.0f);
    }
}

extern "C" void kernel_launch(void* const* d_in, const int* in_sizes, int n_in,
                              void* d_out, int out_size, void* d_ws, size_t ws_size,
                              hipStream_t stream) {
    const float* x = (const float*)d_in[0];
    float* out = (float*)d_out;

    // ws: parent1 [NRUN u32] | parent2 [NRUN u32] | cols [NCOL u32] | closed [NCOL u16]
    const size_t sz_parent = (size_t)NRUN * 4;
    const size_t sz_cols   = (size_t)NCOL * 4;
    const size_t sz_closed = (size_t)NCOL * 2;
    if (ws_size < 2 * sz_parent + sz_cols + sz_closed) return;
    char* ws = (char*)d_ws;
    unsigned*       parent1 = (unsigned*)ws;
    unsigned*       parent2 = (unsigned*)(ws + sz_parent);
    unsigned*       cols    = (unsigned*)(ws + 2 * sz_parent);
    unsigned short* closed  = (unsigned short*)(ws + 2 * sz_parent + sz_cols);

    dim3 blk(256);
    dim3 grdC(NBLK_COL), grdQ(NBLK_QUAD);

    // ---- phase 1: weak-run CCL + hysteresis ----
    k_cols<<<grdQ, blk, 0, stream>>>(x, cols, parent1);
    k_union1<<<grdC, blk, 0, stream>>>(cols, parent1);
    k_agg1<<<grdC, blk, 0, stream>>>(cols, parent1);
    k_close<<<grdC, blk, 0, stream>>>(cols, parent1, closed, parent2);

    // ---- phase 2: closed-run CCL + dust removal ----
    k_union2<<<grdC, blk, 0, stream>>>(closed, parent2);
    k_agg2<<<grdC, blk, 0, stream>>>(closed, parent2);
    k_out<<<grdQ, blk, 0, stream>>>(closed, parent2, out);
}

// Round 6
// 409.315 us; speedup vs baseline: 1.4539x; 1.4539x over previous
//
#include <hip/hip_runtime.h>
#include <stdint.h>

// Fixed problem shape: outputs [8,16,384,384] fp32
#define B_ 8
#define D_ 16
#define H_ 384
#define W_ 384
constexpr int HW   = H_ * W_;     // 147456
constexpr int DHW  = D_ * HW;     // 2359296
constexpr int NCOL = B_ * HW;     // 1179648 columns
// Stratified run ids: id = run_idx * NCOL + column. Real runs concentrate in
// strata 0..2 -> touched parent lines ~3x fewer than column*8+idx layout.
constexpr unsigned NRUN = (unsigned)NCOL * 8u;

constexpr float T_LOW  = 0.8f;
constexpr float T_HIGH = 0.92f;
constexpr unsigned DUST_MIN = 20u;

constexpr int NBLK_COL  = NCOL / 256;   // 4608
constexpr int NBLK_QUAD = NCOL / 1024;  // 1152
constexpr int PH = H_ / 16, PW = W_ / 16;          // 24 x 24 patches
constexpr int NBLK_PATCH = B_ * PH * PW;           // 4608

// ---------- global union-find over stratified z-run ids ----------
// parent[] : value < NRUN -> parent pointer; value >= NRUN -> root,
// aggregated count = 0xFFFFFFFF - value (init 0xFFFFFFFF => root, count 0).
// Path-halving stores only values < NRUN (parent pointers), so root count
// encodings can never be written into non-root slots; parents decrease
// monotonically so all read/store races remain valid shortcuts.
__device__ __forceinline__ unsigned gfind(unsigned* A, unsigned x) {
    for (;;) {
        unsigned p = A[x];
        if (p >= NRUN) return x;
        unsigned g = A[p];
        if (g >= NRUN) return p;
        A[x] = g;          // halve
        x = g;
    }
}

__device__ __forceinline__ unsigned groot_val(unsigned* A, unsigned x) {
    for (;;) {
        unsigned p = A[x];
        if (p >= NRUN) return p;
        unsigned g = A[p];
        if (g >= NRUN) return g;
        A[x] = g;          // halve
        x = g;
    }
}

__device__ __forceinline__ void gunite(unsigned* A, unsigned a, unsigned b) {
    for (;;) {
        a = gfind(A, a);
        b = gfind(A, b);
        if (a == b) return;
        unsigned lo = a < b ? a : b;
        unsigned hi = a < b ? b : a;
        unsigned old = atomicMin(&A[hi], lo);
        if (old >= NRUN) return;
        a = lo; b = old;
    }
}

// run index containing set bit p of mask m
__device__ __forceinline__ int runidx(unsigned m, int p) {
    unsigned starts = m & ~(m << 1);
    return __popc(starts & ((2u << p) - 1u)) - 1;
}

__device__ __forceinline__ void unite_overlaps(unsigned* parent, int cA, unsigned mA,
                                               int cB, unsigned mB) {
    unsigned ov = mA & mB;
    while (ov) {
        int p = __ffs(ov) - 1;
        gunite(parent, (unsigned)runidx(mA, p) * NCOL + cA,
                       (unsigned)runidx(mB, p) * NCOL + cB);
        ov &= ov + (1u << p);   // clear this contiguous overlap segment
    }
}

// number of runs in a 16-bit mask
__device__ __forceinline__ int nruns(unsigned m) {
    return __popc(m & ~(m << 1));
}

// ---------- LDS hash: per-block pre-aggregation of (root -> count) ----------
__device__ __forceinline__ void hash_insert(unsigned* hkey, unsigned* hval,
                                            unsigned* parent, unsigned root, unsigned cnt) {
    unsigned s = (root * 2654435761u) >> 22;   // top 10 bits
    for (int probes = 0; probes < 64; ++probes) {
        unsigned idx = s & 1023u;
        unsigned k = hkey[idx];
        if (k == root) { atomicAdd(&hval[idx], cnt); return; }
        if (k == 0xFFFFFFFFu) {
            unsigned old = atomicCAS(&hkey[idx], 0xFFFFFFFFu, root);
            if (old == 0xFFFFFFFFu || old == root) { atomicAdd(&hval[idx], cnt); return; }
        }
        ++s;
    }
    atomicSub(&parent[root], cnt);   // table overflow fallback
}

// ---------------- kernels ----------------

// x -> packed weak|strong column masks (4 cols/thread, float4); lazy-init
// parent1 for existing weak runs only (unreachable slots stay poisoned).
__global__ __launch_bounds__(256) void k_cols(const float* __restrict__ x,
                                              unsigned* __restrict__ cols,
                                              unsigned* __restrict__ parent1) {
    int q = blockIdx.x * 256 + threadIdx.x;       // 0..NCOL/4-1
    int c0 = q * 4;
    int b = c0 / HW, off = c0 - b * HW;
    const float* xp = x + (size_t)b * DHW + off;
    unsigned wk[4] = {0, 0, 0, 0}, st[4] = {0, 0, 0, 0};
    #pragma unroll
    for (int z = 0; z < D_; ++z) {
        float4 v = *(const float4*)(xp + (size_t)z * HW);
        wk[0] |= (v.x >= T_LOW  ? 1u : 0u) << z;  st[0] |= (v.x >= T_HIGH ? 1u : 0u) << z;
        wk[1] |= (v.y >= T_LOW  ? 1u : 0u) << z;  st[1] |= (v.y >= T_HIGH ? 1u : 0u) << z;
        wk[2] |= (v.z >= T_LOW  ? 1u : 0u) << z;  st[2] |= (v.z >= T_HIGH ? 1u : 0u) << z;
        wk[3] |= (v.w >= T_LOW  ? 1u : 0u) << z;  st[3] |= (v.w >= T_HIGH ? 1u : 0u) << z;
    }
    *(uint4*)(cols + c0) = make_uint4(wk[0] | (st[0] << 16), wk[1] | (st[1] << 16),
                                      wk[2] | (st[2] << 16), wk[3] | (st[3] << 16));
    #pragma unroll
    for (int j = 0; j < 4; ++j) {
        int nr = nruns(wk[j]);
        for (int i = 0; i < nr; ++i)
            parent1[(unsigned)i * NCOL + (c0 + j)] = 0xFFFFFFFFu;
    }
}

// unions between overlapping weak runs of (c,c+1) and (c,c+W)
__global__ __launch_bounds__(256) void k_union1(const unsigned* __restrict__ cols,
                                                unsigned* parent1) {
    int c = blockIdx.x * 256 + threadIdx.x;
    unsigned mA = cols[c] & 0xFFFFu;
    if (!mA) return;
    int w = c % W_;
    int h = (c / W_) % H_;
    if (w < W_ - 1) {
        unsigned mB = cols[c + 1] & 0xFFFFu;
        if (mA & mB) unite_overlaps(parent1, c, mA, c + 1, mB);
    }
    if (h < H_ - 1) {
        unsigned mB = cols[c + W_] & 0xFFFFu;
        if (mA & mB) unite_overlaps(parent1, c, mA, c + W_, mB);
    }
}

// aggregate per-run strong counts into roots (16x16 patch + LDS hash dedup)
__global__ __launch_bounds__(256) void k_agg1(const unsigned* __restrict__ cols,
                                              unsigned* parent1) {
    __shared__ unsigned hkey[1024];
    __shared__ unsigned hval[1024];
    for (int i = threadIdx.x; i < 1024; i += 256) { hkey[i] = 0xFFFFFFFFu; hval[i] = 0; }
    __syncthreads();
    int blk = blockIdx.x;
    int b = blk / (PH * PW), pr = blk % (PH * PW);
    int h = (pr / PW) * 16 + (threadIdx.x >> 4);
    int w = (pr % PW) * 16 + (threadIdx.x & 15);
    int c = b * HW + h * W_ + w;
    unsigned cc = cols[c];
    unsigned wk = cc & 0xFFFFu, st = cc >> 16;
    if (st) {
        unsigned rem = wk; int idx = 0;
        while (rem) {
            int p = __ffs(rem) - 1;
            unsigned tt = rem >> p;
            int len = __ffs(~tt) - 1;
            unsigned runmask = ((1u << len) - 1u) << p;
            unsigned sc = (unsigned)__popc(runmask & st);
            if (sc) {
                unsigned r = gfind(parent1, (unsigned)idx * NCOL + c);
                hash_insert(hkey, hval, parent1, r, sc);
            }
            rem &= ~runmask; ++idx;
        }
    }
    __syncthreads();
    for (int i = threadIdx.x; i < 1024; i += 256)
        if (hkey[i] != 0xFFFFFFFFu && hval[i])
            atomicSub(&parent1[hkey[i]], hval[i]);
}

// hysteresis + z-closing -> closed masks; lazy-init parent2 for closed runs
__global__ __launch_bounds__(256) void k_close(const unsigned* __restrict__ cols,
                                               unsigned* parent1,
                                               unsigned short* __restrict__ closed,
                                               unsigned* __restrict__ parent2) {
    int c = blockIdx.x * 256 + threadIdx.x;
    unsigned wk = cols[c] & 0xFFFFu;
    unsigned m = 0;
    unsigned rem = wk; int idx = 0;
    while (rem) {
        int p = __ffs(rem) - 1;
        unsigned tt = rem >> p;
        int len = __ffs(~tt) - 1;
        unsigned runmask = ((1u << len) - 1u) << p;
        if (groot_val(parent1, (unsigned)idx * NCOL + c) != 0xFFFFFFFFu)  // strong > 0
            m |= runmask;
        rem &= ~runmask; ++idx;
    }
    // z-closing: dilate (OOB = background), erode (OOB = foreground)
    unsigned dil = (m | (m << 1) | (m >> 1)) & 0xFFFFu;
    unsigned ero = dil & ((dil << 1) | 1u) & ((dil >> 1) | 0x8000u);
    closed[c] = (unsigned short)ero;
    int nr = nruns(ero);
    for (int i = 0; i < nr; ++i)
        parent2[(unsigned)i * NCOL + c] = 0xFFFFFFFFu;
}

// unions between overlapping closed runs
__global__ __launch_bounds__(256) void k_union2(const unsigned short* __restrict__ closed,
                                                unsigned* parent2) {
    int c = blockIdx.x * 256 + threadIdx.x;
    unsigned mA = closed[c];
    if (!mA) return;
    int w = c % W_;
    int h = (c / W_) % H_;
    if (w < W_ - 1) {
        unsigned mB = closed[c + 1];
        if (mA & mB) unite_overlaps(parent2, c, mA, c + 1, mB);
    }
    if (h < H_ - 1) {
        unsigned mB = closed[c + W_];
        if (mA & mB) unite_overlaps(parent2, c, mA, c + W_, mB);
    }
}

// aggregate per-run voxel counts into roots (16x16 patch + LDS hash dedup)
__global__ __launch_bounds__(256) void k_agg2(const unsigned short* __restrict__ closed,
                                              unsigned* parent2) {
    __shared__ unsigned hkey[1024];
    __shared__ unsigned hval[1024];
    for (int i = threadIdx.x; i < 1024; i += 256) { hkey[i] = 0xFFFFFFFFu; hval[i] = 0; }
    __syncthreads();
    int blk = blockIdx.x;
    int b = blk / (PH * PW), pr = blk % (PH * PW);
    int h = (pr / PW) * 16 + (threadIdx.x >> 4);
    int w = (pr % PW) * 16 + (threadIdx.x & 15);
    int c = b * HW + h * W_ + w;
    unsigned fg = closed[c];
    if (fg) {
        unsigned rem = fg; int idx = 0;
        while (rem) {
            int p = __ffs(rem) - 1;
            unsigned tt = rem >> p;
            int len = __ffs(~tt) - 1;
            unsigned runmask = ((1u << len) - 1u) << p;
            unsigned r = gfind(parent2, (unsigned)idx * NCOL + c);
            hash_insert(hkey, hval, parent2, r, (unsigned)__popc(runmask));
            rem &= ~runmask; ++idx;
        }
    }
    __syncthreads();
    for (int i = threadIdx.x; i < 1024; i += 256)
        if (hkey[i] != 0xFFFFFFFFu && hval[i])
            atomicSub(&parent2[hkey[i]], hval[i]);
}

// keep components with size >= DUST_MIN; write 0/1 float (4 cols/thread)
__global__ __launch_bounds__(256) void k_out(const unsigned short* __restrict__ closed,
                                             unsigned* parent2,
                                             float* __restrict__ out) {
    int q = blockIdx.x * 256 + threadIdx.x;
    int c0 = q * 4;
    int b = c0 / HW, off = c0 - b * HW;
    unsigned keep[4];
    #pragma unroll
    for (int j = 0; j < 4; ++j) {
        int c = c0 + j;
        unsigned fg = closed[c];
        unsigned k = 0;
        unsigned rem = fg; int idx = 0;
        while (rem) {
            int p = __ffs(rem) - 1;
            unsigned tt = rem >> p;
            int len = __ffs(~tt) - 1;
            unsigned runmask = ((1u << len) - 1u) << p;
            if (0xFFFFFFFFu - groot_val(parent2, (unsigned)idx * NCOL + c) >= DUST_MIN)
                k |= runmask;
            rem &= ~runmask; ++idx;
        }
        keep[j] = k;
    }
    float* op = out + (size_t)b * DHW + off;
    #pragma unroll
    for (int z = 0; z < D_; ++z) {
        *(float4*)(op + (size_t)z * HW) =
            make_float4((keep[0] >> z) & 1u ? 1.0f : 0.0f,
                        (keep[1] >> z) & 1u ? 1.0f : 0.0f,
                        (keep[2] >> z) & 1u ? 1.0f : 0.0f,
                        (keep[3] >> z) & 1u ? 1.0f : 0.0f);
    }
}

extern "C" void kernel_launch(void* const* d_in, const int* in_sizes, int n_in,
                              void* d_out, int out_size, void* d_ws, size_t ws_size,
                              hipStream_t stream) {
    const float* x = (const float*)d_in[0];
    float* out = (float*)d_out;

    // ws: parent1 [NRUN u32] | parent2 [NRUN u32] | cols [NCOL u32] | closed [NCOL u16]
    const size_t sz_parent = (size_t)NRUN * 4;
    const size_t sz_cols   = (size_t)NCOL * 4;
    const size_t sz_closed = (size_t)NCOL * 2;
    if (ws_size < 2 * sz_parent + sz_cols + sz_closed) return;
    char* ws = (char*)d_ws;
    unsigned*       parent1 = (unsigned*)ws;
    unsigned*       parent2 = (unsigned*)(ws + sz_parent);
    unsigned*       cols    = (unsigned*)(ws + 2 * sz_parent);
    unsigned short* closed  = (unsigned short*)(ws + 2 * sz_parent + sz_cols);

    dim3 blk(256);
    dim3 grdC(NBLK_COL), grdQ(NBLK_QUAD), grdP(NBLK_PATCH);

    // ---- phase 1: weak-run CCL + hysteresis ----
    k_cols<<<grdQ, blk, 0, stream>>>(x, cols, parent1);
    k_union1<<<grdC, blk, 0, stream>>>(cols, parent1);
    k_agg1<<<grdP, blk, 0, stream>>>(cols, parent1);
    k_close<<<grdC, blk, 0, stream>>>(cols, parent1, closed, parent2);

    // ---- phase 2: closed-run CCL + dust removal ----
    k_union2<<<grdC, blk, 0, stream>>>(closed, parent2);
    k_agg2<<<grdP, blk, 0, stream>>>(closed, parent2);
    k_out<<<grdQ, blk, 0, stream>>>(closed, parent2, out);
}

// Round 7
// 322.554 us; speedup vs baseline: 1.8449x; 1.2690x over previous
//
#include <hip/hip_runtime.h>
#include <stdint.h>

// Fixed problem shape: outputs [8,16,384,384] fp32
#define B_ 8
#define D_ 16
#define H_ 384
#define W_ 384
constexpr int HW   = H_ * W_;     // 147456
constexpr int DHW  = D_ * HW;     // 2359296
constexpr int NCOL = B_ * HW;     // 1179648 columns
// Stratified run ids: id = run_idx * NCOL + column (runs concentrate in strata 0..2)
constexpr unsigned NRUN = (unsigned)NCOL * 8u;

constexpr float T_LOW  = 0.8f;
constexpr float T_HIGH = 0.92f;
constexpr unsigned DUST_MIN = 20u;

constexpr int NBLK_COL  = NCOL / 256;   // 4608
constexpr int NBLK_QUAD = NCOL / 1024;  // 1152

// hash-agg patches (16x16 cols)
constexpr int PH = H_ / 16, PW = W_ / 16;          // 24 x 24
constexpr int NBLK_PATCH = B_ * PH * PW;           // 4608

// local-UF patches (32x8 cols, 256 threads = 1 col/thread)
constexpr int PTW = 32, PTH = 8;
constexpr int PWB = W_ / PTW;             // 12
constexpr int PHB = H_ / PTH;             // 48
constexpr int NPATCH = B_ * PWB * PHB;    // 4608

// boundary column-pairs between local-UF patches
constexpr int WPAIR_B = (PWB - 1) * H_;   // 11*384 = 4224
constexpr int HPAIR_B = (PHB - 1) * W_;   // 47*384 = 18048
constexpr int PAIR_B  = WPAIR_B + HPAIR_B;   // 22272
constexpr int NPAIRS  = B_ * PAIR_B;         // 178176

// ---------- global union-find over stratified z-run ids ----------
// parent[] : value < NRUN -> parent pointer; value >= NRUN -> root,
// aggregated count = 0xFFFFFFFF - value. Parents only ever decrease.
__device__ __forceinline__ unsigned gfind(unsigned* A, unsigned x) {
    for (;;) {
        unsigned p = A[x];
        if (p >= NRUN) return x;
        unsigned g = A[p];
        if (g >= NRUN) return p;
        A[x] = g;          // path halving (stores only values < NRUN)
        x = g;
    }
}

__device__ __forceinline__ unsigned groot_val(unsigned* A, unsigned x) {
    for (;;) {
        unsigned p = A[x];
        if (p >= NRUN) return p;
        unsigned g = A[p];
        if (g >= NRUN) return g;
        A[x] = g;
        x = g;
    }
}

__device__ __forceinline__ void gunite(unsigned* A, unsigned a, unsigned b) {
    for (;;) {
        a = gfind(A, a);
        b = gfind(A, b);
        if (a == b) return;
        unsigned lo = a < b ? a : b;
        unsigned hi = a < b ? b : a;
        unsigned old = atomicMin(&A[hi], lo);
        if (old >= NRUN) return;
        a = lo; b = old;
    }
}

// run index containing set bit p of mask m
__device__ __forceinline__ int runidx(unsigned m, int p) {
    unsigned starts = m & ~(m << 1);
    return __popc(starts & ((2u << p) - 1u)) - 1;
}

__device__ __forceinline__ int nruns(unsigned m) {
    return __popc(m & ~(m << 1));
}

__device__ __forceinline__ void unite_overlaps(unsigned* parent, int cA, unsigned mA,
                                               int cB, unsigned mB) {
    unsigned ov = mA & mB;
    while (ov) {
        int p = __ffs(ov) - 1;
        gunite(parent, (unsigned)runidx(mA, p) * NCOL + cA,
                       (unsigned)runidx(mB, p) * NCOL + cB);
        ov &= ov + (1u << p);
    }
}

// ---------- patch-local LDS union-find (ids: run_idx*256 + thread) ----------
__device__ __forceinline__ unsigned luf_find(unsigned* su, unsigned x) {
    unsigned p = su[x];
    while (p != x) { x = p; p = su[x]; }
    return x;
}

__device__ __forceinline__ void luf_union(unsigned* su, unsigned a, unsigned b) {
    for (;;) {
        a = luf_find(su, a);
        b = luf_find(su, b);
        if (a == b) return;
        unsigned lo = a < b ? a : b;
        unsigned hi = a < b ? b : a;
        unsigned old = atomicMin(&su[hi], lo);
        if (old == hi) return;
        a = lo; b = old;
    }
}

// Local UF over one 32x8 patch, then write EVERY existing run's parent entry:
// local root -> 0xFFFFFFFF (root, count 0); other -> link to local root's gid
// (patch-local min gid, keeps parents monotone decreasing). Plain stores:
// each entry owned by exactly one patch. Cross-patch edges: separate kernel.
__device__ __forceinline__ void local_uf_patch(unsigned m, unsigned* parent,
                                               int b, int h0, int w0, int t) {
    __shared__ unsigned sm[256];
    __shared__ unsigned su[2048];
    int lw = t & 31, lh = t >> 5;
    int c = b * HW + (h0 + lh) * W_ + (w0 + lw);
    sm[t] = m;
    #pragma unroll
    for (int i = 0; i < 8; ++i) su[i * 256 + t] = i * 256 + t;
    __syncthreads();
    if (m) {
        if (lw < 31) {
            unsigned mB = sm[t + 1];
            unsigned ov = m & mB;
            while (ov) {
                int p = __ffs(ov) - 1;
                luf_union(su, (unsigned)runidx(m, p) * 256 + t,
                              (unsigned)runidx(mB, p) * 256 + t + 1);
                ov &= ov + (1u << p);
            }
        }
        if (lh < 7) {
            unsigned mB = sm[t + 32];
            unsigned ov = m & mB;
            while (ov) {
                int p = __ffs(ov) - 1;
                luf_union(su, (unsigned)runidx(m, p) * 256 + t,
                              (unsigned)runidx(mB, p) * 256 + t + 32);
                ov &= ov + (1u << p);
            }
        }
    }
    __syncthreads();
    int nr = nruns(m);
    for (int i = 0; i < nr; ++i) {
        unsigned lid = (unsigned)i * 256 + t;
        unsigned lr  = luf_find(su, lid);
        unsigned gid = (unsigned)i * NCOL + c;
        if (lr == lid) parent[gid] = 0xFFFFFFFFu;
        else {
            unsigned tt = lr & 255u, ss = lr >> 8;
            parent[gid] = ss * NCOL +
                (unsigned)(b * HW + (h0 + (int)(tt >> 5)) * W_ + (w0 + (int)(tt & 31)));
        }
    }
}

// ---------- LDS hash: per-block (root -> count) pre-aggregation ----------
__device__ __forceinline__ void hash_insert(unsigned* hkey, unsigned* hval,
                                            unsigned* parent, unsigned root, unsigned cnt) {
    unsigned s = (root * 2654435761u) >> 22;
    for (int probes = 0; probes < 64; ++probes) {
        unsigned idx = s & 1023u;
        unsigned k = hkey[idx];
        if (k == root) { atomicAdd(&hval[idx], cnt); return; }
        if (k == 0xFFFFFFFFu) {
            unsigned old = atomicCAS(&hkey[idx], 0xFFFFFFFFu, root);
            if (old == 0xFFFFFFFFu || old == root) { atomicAdd(&hval[idx], cnt); return; }
        }
        ++s;
    }
    atomicSub(&parent[root], cnt);
}

// ---------------- kernels ----------------

// x -> packed weak|strong column masks (4 cols/thread, float4)
__global__ __launch_bounds__(256) void k_cols(const float* __restrict__ x,
                                              unsigned* __restrict__ cols) {
    int q = blockIdx.x * 256 + threadIdx.x;
    int c0 = q * 4;
    int b = c0 / HW, off = c0 - b * HW;
    const float* xp = x + (size_t)b * DHW + off;
    unsigned wk[4] = {0, 0, 0, 0}, st[4] = {0, 0, 0, 0};
    #pragma unroll
    for (int z = 0; z < D_; ++z) {
        float4 v = *(const float4*)(xp + (size_t)z * HW);
        wk[0] |= (v.x >= T_LOW  ? 1u : 0u) << z;  st[0] |= (v.x >= T_HIGH ? 1u : 0u) << z;
        wk[1] |= (v.y >= T_LOW  ? 1u : 0u) << z;  st[1] |= (v.y >= T_HIGH ? 1u : 0u) << z;
        wk[2] |= (v.z >= T_LOW  ? 1u : 0u) << z;  st[2] |= (v.z >= T_HIGH ? 1u : 0u) << z;
        wk[3] |= (v.w >= T_LOW  ? 1u : 0u) << z;  st[3] |= (v.w >= T_HIGH ? 1u : 0u) << z;
    }
    *(uint4*)(cols + c0) = make_uint4(wk[0] | (st[0] << 16), wk[1] | (st[1] << 16),
                                      wk[2] | (st[2] << 16), wk[3] | (st[3] << 16));
}

// patch-local UF on weak masks; writes all parent1 entries
__global__ __launch_bounds__(256) void k_loc1(const unsigned* __restrict__ cols,
                                              unsigned* __restrict__ parent1) {
    int blk = blockIdx.x;
    int b = blk / (PHB * PWB), pr = blk % (PHB * PWB);
    int h0 = (pr / PWB) * PTH, w0 = (pr % PWB) * PTW;
    int t = threadIdx.x;
    int c = b * HW + (h0 + (t >> 5)) * W_ + (w0 + (t & 31));
    local_uf_patch(cols[c] & 0xFFFFu, parent1, b, h0, w0, t);
}

// cross-patch boundary unions (weak)
__global__ __launch_bounds__(256) void k_bnd1(const unsigned* __restrict__ cols,
                                              unsigned* parent1) {
    int e = blockIdx.x * 256 + threadIdx.x;
    if (e >= NPAIRS) return;
    int b = e / PAIR_B, r = e % PAIR_B;
    int cA, cB;
    if (r < WPAIR_B) {
        int h = r / (PWB - 1), wi = r % (PWB - 1);
        cA = b * HW + h * W_ + wi * PTW + (PTW - 1);
        cB = cA + 1;
    } else {
        r -= WPAIR_B;
        int hi = r / W_, w = r % W_;
        cA = b * HW + (hi * PTH + (PTH - 1)) * W_ + w;
        cB = cA + W_;
    }
    unsigned mA = cols[cA] & 0xFFFFu;
    unsigned mB = cols[cB] & 0xFFFFu;
    if (mA & mB) unite_overlaps(parent1, cA, mA, cB, mB);
}

// aggregate per-run strong counts into roots (16x16 patch + LDS hash dedup)
__global__ __launch_bounds__(256) void k_agg1(const unsigned* __restrict__ cols,
                                              unsigned* parent1) {
    __shared__ unsigned hkey[1024];
    __shared__ unsigned hval[1024];
    for (int i = threadIdx.x; i < 1024; i += 256) { hkey[i] = 0xFFFFFFFFu; hval[i] = 0; }
    __syncthreads();
    int blk = blockIdx.x;
    int b = blk / (PH * PW), pr = blk % (PH * PW);
    int h = (pr / PW) * 16 + (threadIdx.x >> 4);
    int w = (pr % PW) * 16 + (threadIdx.x & 15);
    int c = b * HW + h * W_ + w;
    unsigned cc = cols[c];
    unsigned wk = cc & 0xFFFFu, st = cc >> 16;
    if (st) {
        unsigned rem = wk; int idx = 0;
        while (rem) {
            int p = __ffs(rem) - 1;
            unsigned tt = rem >> p;
            int len = __ffs(~tt) - 1;
            unsigned runmask = ((1u << len) - 1u) << p;
            unsigned sc = (unsigned)__popc(runmask & st);
            if (sc) {
                unsigned r = gfind(parent1, (unsigned)idx * NCOL + c);
                hash_insert(hkey, hval, parent1, r, sc);
            }
            rem &= ~runmask; ++idx;
        }
    }
    __syncthreads();
    for (int i = threadIdx.x; i < 1024; i += 256)
        if (hkey[i] != 0xFFFFFFFFu && hval[i])
            atomicSub(&parent1[hkey[i]], hval[i]);
}

// hysteresis + z-closing -> closed masks
__global__ __launch_bounds__(256) void k_close(const unsigned* __restrict__ cols,
                                               unsigned* parent1,
                                               unsigned short* __restrict__ closed) {
    int c = blockIdx.x * 256 + threadIdx.x;
    unsigned wk = cols[c] & 0xFFFFu;
    unsigned m = 0;
    unsigned rem = wk; int idx = 0;
    while (rem) {
        int p = __ffs(rem) - 1;
        unsigned tt = rem >> p;
        int len = __ffs(~tt) - 1;
        unsigned runmask = ((1u << len) - 1u) << p;
        if (groot_val(parent1, (unsigned)idx * NCOL + c) != 0xFFFFFFFFu)  // strong > 0
            m |= runmask;
        rem &= ~runmask; ++idx;
    }
    unsigned dil = (m | (m << 1) | (m >> 1)) & 0xFFFFu;
    unsigned ero = dil & ((dil << 1) | 1u) & ((dil >> 1) | 0x8000u);
    closed[c] = (unsigned short)ero;
}

// patch-local UF on closed masks; writes all parent2 entries
__global__ __launch_bounds__(256) void k_loc2(const unsigned short* __restrict__ closed,
                                              unsigned* __restrict__ parent2) {
    int blk = blockIdx.x;
    int b = blk / (PHB * PWB), pr = blk % (PHB * PWB);
    int h0 = (pr / PWB) * PTH, w0 = (pr % PWB) * PTW;
    int t = threadIdx.x;
    int c = b * HW + (h0 + (t >> 5)) * W_ + (w0 + (t & 31));
    local_uf_patch((unsigned)closed[c], parent2, b, h0, w0, t);
}

// cross-patch boundary unions (closed)
__global__ __launch_bounds__(256) void k_bnd2(const unsigned short* __restrict__ closed,
                                              unsigned* parent2) {
    int e = blockIdx.x * 256 + threadIdx.x;
    if (e >= NPAIRS) return;
    int b = e / PAIR_B, r = e % PAIR_B;
    int cA, cB;
    if (r < WPAIR_B) {
        int h = r / (PWB - 1), wi = r % (PWB - 1);
        cA = b * HW + h * W_ + wi * PTW + (PTW - 1);
        cB = cA + 1;
    } else {
        r -= WPAIR_B;
        int hi = r / W_, w = r % W_;
        cA = b * HW + (hi * PTH + (PTH - 1)) * W_ + w;
        cB = cA + W_;
    }
    unsigned mA = closed[cA];
    unsigned mB = closed[cB];
    if (mA & mB) unite_overlaps(parent2, cA, mA, cB, mB);
}

// aggregate per-run voxel counts into roots (16x16 patch + LDS hash dedup)
__global__ __launch_bounds__(256) void k_agg2(const unsigned short* __restrict__ closed,
                                              unsigned* parent2) {
    __shared__ unsigned hkey[1024];
    __shared__ unsigned hval[1024];
    for (int i = threadIdx.x; i < 1024; i += 256) { hkey[i] = 0xFFFFFFFFu; hval[i] = 0; }
    __syncthreads();
    int blk = blockIdx.x;
    int b = blk / (PH * PW), pr = blk % (PH * PW);
    int h = (pr / PW) * 16 + (threadIdx.x >> 4);
    int w = (pr % PW) * 16 + (threadIdx.x & 15);
    int c = b * HW + h * W_ + w;
    unsigned fg = closed[c];
    if (fg) {
        unsigned rem = fg; int idx = 0;
        while (rem) {
            int p = __ffs(rem) - 1;
            unsigned tt = rem >> p;
            int len = __ffs(~tt) - 1;
            unsigned runmask = ((1u << len) - 1u) << p;
            unsigned r = gfind(parent2, (unsigned)idx * NCOL + c);
            hash_insert(hkey, hval, parent2, r, (unsigned)__popc(runmask));
            rem &= ~runmask; ++idx;
        }
    }
    __syncthreads();
    for (int i = threadIdx.x; i < 1024; i += 256)
        if (hkey[i] != 0xFFFFFFFFu && hval[i])
            atomicSub(&parent2[hkey[i]], hval[i]);
}

// keep components with size >= DUST_MIN; write 0/1 float (4 cols/thread)
__global__ __launch_bounds__(256) void k_out(const unsigned short* __restrict__ closed,
                                             unsigned* parent2,
                                             float* __restrict__ out) {
    int q = blockIdx.x * 256 + threadIdx.x;
    int c0 = q * 4;
    int b = c0 / HW, off = c0 - b * HW;
    unsigned keep[4];
    #pragma unroll
    for (int j = 0; j < 4; ++j) {
        int c = c0 + j;
        unsigned fg = closed[c];
        unsigned k = 0;
        unsigned rem = fg; int idx = 0;
        while (rem) {
            int p = __ffs(rem) - 1;
            unsigned tt = rem >> p;
            int len = __ffs(~tt) - 1;
            unsigned runmask = ((1u << len) - 1u) << p;
            if (0xFFFFFFFFu - groot_val(parent2, (unsigned)idx * NCOL + c) >= DUST_MIN)
                k |= runmask;
            rem &= ~runmask; ++idx;
        }
        keep[j] = k;
    }
    float* op = out + (size_t)b * DHW + off;
    #pragma unroll
    for (int z = 0; z < D_; ++z) {
        *(float4*)(op + (size_t)z * HW) =
            make_float4((keep[0] >> z) & 1u ? 1.0f : 0.0f,
                        (keep[1] >> z) & 1u ? 1.0f : 0.0f,
                        (keep[2] >> z) & 1u ? 1.0f : 0.0f,
                        (keep[3] >> z) & 1u ? 1.0f : 0.0f);
    }
}

extern "C" void kernel_launch(void* const* d_in, const int* in_sizes, int n_in,
                              void* d_out, int out_size, void* d_ws, size_t ws_size,
                              hipStream_t stream) {
    const float* x = (const float*)d_in[0];
    float* out = (float*)d_out;

    // ws: parent1 [NRUN u32] | parent2 [NRUN u32] | cols [NCOL u32] | closed [NCOL u16]
    const size_t sz_parent = (size_t)NRUN * 4;
    const size_t sz_cols   = (size_t)NCOL * 4;
    const size_t sz_closed = (size_t)NCOL * 2;
    if (ws_size < 2 * sz_parent + sz_cols + sz_closed) return;
    char* ws = (char*)d_ws;
    unsigned*       parent1 = (unsigned*)ws;
    unsigned*       parent2 = (unsigned*)(ws + sz_parent);
    unsigned*       cols    = (unsigned*)(ws + 2 * sz_parent);
    unsigned short* closed  = (unsigned short*)(ws + 2 * sz_parent + sz_cols);

    dim3 blk(256);
    dim3 grdC(NBLK_COL), grdQ(NBLK_QUAD), grdP(NBLK_PATCH), grdL(NPATCH);
    dim3 grdB((NPAIRS + 255) / 256);

    // ---- phase 1: weak-run CCL + hysteresis ----
    k_cols<<<grdQ, blk, 0, stream>>>(x, cols);
    k_loc1<<<grdL, blk, 0, stream>>>(cols, parent1);
    k_bnd1<<<grdB, blk, 0, stream>>>(cols, parent1);
    k_agg1<<<grdP, blk, 0, stream>>>(cols, parent1);
    k_close<<<grdC, blk, 0, stream>>>(cols, parent1, closed);

    // ---- phase 2: closed-run CCL + dust removal ----
    k_loc2<<<grdL, blk, 0, stream>>>(closed, parent2);
    k_bnd2<<<grdB, blk, 0, stream>>>(closed, parent2);
    k_agg2<<<grdP, blk, 0, stream>>>(closed, parent2);
    k_out<<<grdQ, blk, 0, stream>>>(closed, parent2, out);
}

// Round 8
// 278.608 us; speedup vs baseline: 2.1359x; 1.1577x over previous
//
#include <hip/hip_runtime.h>
#include <stdint.h>

// Fixed problem shape: outputs [8,16,384,384] fp32
#define B_ 8
#define D_ 16
#define H_ 384
#define W_ 384
constexpr int HW   = H_ * W_;     // 147456
constexpr int DHW  = D_ * HW;     // 2359296
constexpr int NCOL = B_ * HW;     // 1179648 columns
// Stratified run ids: id = run_idx * NCOL + column (runs concentrate in strata 0..2)
constexpr unsigned NRUN = (unsigned)NCOL * 8u;

constexpr float T_LOW  = 0.8f;
constexpr float T_HIGH = 0.92f;
constexpr unsigned DUST_MIN = 20u;
constexpr unsigned FLAGGED = 0xFFFFFFFEu;   // phase-1 root value: has strong voxel

constexpr int NBLK_QUAD = NCOL / 1024;  // 1152 (4 cols/thread kernels)

// local-UF patches (32x8 cols, 256 threads = 1 col/thread)
constexpr int PTW = 32, PTH = 8;
constexpr int PWB = W_ / PTW;             // 12
constexpr int PHB = H_ / PTH;             // 48
constexpr int NPATCH = B_ * PWB * PHB;    // 4608

// boundary column-pairs between patches
constexpr int WPAIR_B = (PWB - 1) * H_;      // 4224
constexpr int HPAIR_B = (PHB - 1) * W_;      // 18048
constexpr int PAIR_B  = WPAIR_B + HPAIR_B;   // 22272
constexpr int NPAIRS  = B_ * PAIR_B;         // 178176

// ---------- global union-find over stratified z-run ids ----------
// parent[] : value < NRUN -> parent pointer; value >= NRUN -> root encoding.
// Phase 1 roots: 0xFFFFFFFF = no strong, 0xFFFFFFFE = has strong.
// Phase 2 roots: 0xFFFFFFFF - componentVoxelCount.
// Parents only ever decrease; path-halving stores only pointer values.
__device__ __forceinline__ unsigned gfind(unsigned* A, unsigned x) {
    for (;;) {
        unsigned p = A[x];
        if (p >= NRUN) return x;
        unsigned g = A[p];
        if (g >= NRUN) return p;
        A[x] = g;
        x = g;
    }
}

__device__ __forceinline__ unsigned groot_val(unsigned* A, unsigned x) {
    for (;;) {
        unsigned p = A[x];
        if (p >= NRUN) return p;
        unsigned g = A[p];
        if (g >= NRUN) return g;
        A[x] = g;
        x = g;
    }
}

// ensure the root of x's component is flagged (phase 1)
__device__ __forceinline__ void set_flag(unsigned* A, unsigned x) {
    unsigned r = gfind(A, x);
    for (;;) {
        unsigned old = atomicMin(&A[r], FLAGGED);
        if (old >= NRUN) return;        // was a root: now flagged (or already)
        r = gfind(A, old);              // got linked meanwhile: follow
    }
}

// add cnt into the root encoding of x's component (phase 2).
// CAS only succeeds on root-encoded values -> can never corrupt a pointer.
__device__ __forceinline__ void add_count(unsigned* A, unsigned x, unsigned cnt) {
    unsigned r = gfind(A, x);
    for (;;) {
        unsigned old = A[r];
        if (old < NRUN) { r = gfind(A, old); continue; }
        if (atomicCAS(&A[r], old, old - cnt) == old) return;
    }
}

// union with flag propagation (phase 1)
__device__ __forceinline__ void gunite_flag(unsigned* A, unsigned a, unsigned b) {
    for (;;) {
        a = gfind(A, a);
        b = gfind(A, b);
        if (a == b) return;
        unsigned lo = a < b ? a : b;
        unsigned hi = a < b ? b : a;
        unsigned old = atomicMin(&A[hi], lo);
        if (old >= NRUN) {              // hi was a root, now linked under lo
            if (old == FLAGGED) set_flag(A, lo);
            return;
        }
        a = lo; b = old;
    }
}

// union with count propagation (phase 2)
__device__ __forceinline__ void gunite_cnt(unsigned* A, unsigned a, unsigned b) {
    for (;;) {
        a = gfind(A, a);
        b = gfind(A, b);
        if (a == b) return;
        unsigned lo = a < b ? a : b;
        unsigned hi = a < b ? b : a;
        unsigned old = atomicMin(&A[hi], lo);
        if (old >= NRUN) {              // displaced root carried count
            unsigned cnt = 0xFFFFFFFFu - old;
            if (cnt) add_count(A, lo, cnt);
            return;
        }
        a = lo; b = old;
    }
}

// run index containing set bit p of mask m
__device__ __forceinline__ int runidx(unsigned m, int p) {
    unsigned starts = m & ~(m << 1);
    return __popc(starts & ((2u << p) - 1u)) - 1;
}

__device__ __forceinline__ int nruns(unsigned m) {
    return __popc(m & ~(m << 1));
}

// ---------- patch-local LDS union-find (ids: run_idx*256 + thread) ----------
__device__ __forceinline__ unsigned luf_find(unsigned* su, unsigned x) {
    unsigned p = su[x];
    while (p != x) { x = p; p = su[x]; }
    return x;
}

__device__ __forceinline__ void luf_union(unsigned* su, unsigned a, unsigned b) {
    for (;;) {
        a = luf_find(su, a);
        b = luf_find(su, b);
        if (a == b) return;
        unsigned lo = a < b ? a : b;
        unsigned hi = a < b ? b : a;
        unsigned old = atomicMin(&su[hi], lo);
        if (old == hi) return;
        a = lo; b = old;
    }
}

// intra-patch unions for column t against neighbors t+1, t+32 (masks in sm)
__device__ __forceinline__ void patch_unions(unsigned* su, const unsigned* sm,
                                             unsigned m, int t) {
    int lw = t & 31, lh = t >> 5;
    if (!m) return;
    if (lw < 31) {
        unsigned mB = sm[t + 1];
        unsigned ov = m & mB;
        while (ov) {
            int p = __ffs(ov) - 1;
            luf_union(su, (unsigned)runidx(m, p) * 256 + t,
                          (unsigned)runidx(mB, p) * 256 + t + 1);
            ov &= ov + (1u << p);
        }
    }
    if (lh < 7) {
        unsigned mB = sm[t + 32];
        unsigned ov = m & mB;
        while (ov) {
            int p = __ffs(ov) - 1;
            luf_union(su, (unsigned)runidx(m, p) * 256 + t,
                          (unsigned)runidx(mB, p) * 256 + t + 32);
            ov &= ov + (1u << p);
        }
    }
}

// ---------------- kernels ----------------

// x -> packed weak|strong column masks (4 cols/thread, float4)
__global__ __launch_bounds__(256) void k_cols(const float* __restrict__ x,
                                              unsigned* __restrict__ cols) {
    int q = blockIdx.x * 256 + threadIdx.x;
    int c0 = q * 4;
    int b = c0 / HW, off = c0 - b * HW;
    const float* xp = x + (size_t)b * DHW + off;
    unsigned wk[4] = {0, 0, 0, 0}, st[4] = {0, 0, 0, 0};
    #pragma unroll
    for (int z = 0; z < D_; ++z) {
        float4 v = *(const float4*)(xp + (size_t)z * HW);
        wk[0] |= (v.x >= T_LOW  ? 1u : 0u) << z;  st[0] |= (v.x >= T_HIGH ? 1u : 0u) << z;
        wk[1] |= (v.y >= T_LOW  ? 1u : 0u) << z;  st[1] |= (v.y >= T_HIGH ? 1u : 0u) << z;
        wk[2] |= (v.z >= T_LOW  ? 1u : 0u) << z;  st[2] |= (v.z >= T_HIGH ? 1u : 0u) << z;
        wk[3] |= (v.w >= T_LOW  ? 1u : 0u) << z;  st[3] |= (v.w >= T_HIGH ? 1u : 0u) << z;
    }
    *(uint4*)(cols + c0) = make_uint4(wk[0] | (st[0] << 16), wk[1] | (st[1] << 16),
                                      wk[2] | (st[2] << 16), wk[3] | (st[3] << 16));
}

// patch-local UF on weak masks; roots carry strong flag; writes all parent1 entries
__global__ __launch_bounds__(256) void k_loc1(const unsigned* __restrict__ cols,
                                              unsigned* __restrict__ parent1) {
    __shared__ unsigned sm[256];
    __shared__ unsigned su[2048];
    __shared__ unsigned sf[2048];
    int blk = blockIdx.x;
    int b = blk / (PHB * PWB), pr = blk % (PHB * PWB);
    int h0 = (pr / PWB) * PTH, w0 = (pr % PWB) * PTW;
    int t = threadIdx.x;
    int c = b * HW + (h0 + (t >> 5)) * W_ + (w0 + (t & 31));
    unsigned cc = cols[c];
    unsigned m = cc & 0xFFFFu, st = cc >> 16;
    sm[t] = m;
    #pragma unroll
    for (int i = 0; i < 8; ++i) { su[i * 256 + t] = i * 256 + t; sf[i * 256 + t] = 0; }
    __syncthreads();
    patch_unions(su, sm, m, t);
    __syncthreads();
    // mark local roots of strong-containing runs (same-value races benign)
    if (st) {
        unsigned rem = m; int idx = 0;
        while (rem) {
            int p = __ffs(rem) - 1;
            unsigned tt = rem >> p;
            int len = __ffs(~tt) - 1;
            unsigned runmask = ((1u << len) - 1u) << p;
            if (runmask & st) sf[luf_find(su, (unsigned)idx * 256 + t)] = 1u;
            rem &= ~runmask; ++idx;
        }
    }
    __syncthreads();
    int nr = nruns(m);
    for (int i = 0; i < nr; ++i) {
        unsigned lid = (unsigned)i * 256 + t;
        unsigned lr  = luf_find(su, lid);
        unsigned gid = (unsigned)i * NCOL + c;
        if (lr == lid) parent1[gid] = sf[lid] ? FLAGGED : 0xFFFFFFFFu;
        else {
            unsigned tt = lr & 255u, ss = lr >> 8;
            parent1[gid] = ss * NCOL +
                (unsigned)(b * HW + (h0 + (int)(tt >> 5)) * W_ + (w0 + (int)(tt & 31)));
        }
    }
}

// cross-patch boundary unions with flag propagation (weak)
__global__ __launch_bounds__(256) void k_bnd1(const unsigned* __restrict__ cols,
                                              unsigned* parent1) {
    int e = blockIdx.x * 256 + threadIdx.x;
    if (e >= NPAIRS) return;
    int b = e / PAIR_B, r = e % PAIR_B;
    int cA, cB;
    if (r < WPAIR_B) {
        int h = r / (PWB - 1), wi = r % (PWB - 1);
        cA = b * HW + h * W_ + wi * PTW + (PTW - 1);
        cB = cA + 1;
    } else {
        r -= WPAIR_B;
        int hi = r / W_, w = r % W_;
        cA = b * HW + (hi * PTH + (PTH - 1)) * W_ + w;
        cB = cA + W_;
    }
    unsigned mA = cols[cA] & 0xFFFFu;
    unsigned mB = cols[cB] & 0xFFFFu;
    unsigned ov = mA & mB;
    while (ov) {
        int p = __ffs(ov) - 1;
        gunite_flag(parent1, (unsigned)runidx(mA, p) * NCOL + cA,
                             (unsigned)runidx(mB, p) * NCOL + cB);
        ov &= ov + (1u << p);
    }
}

// hysteresis + z-closing (per column) + patch-local UF on closed masks with
// per-local-root voxel counts; writes closed[] and all parent2 entries
__global__ __launch_bounds__(256) void k_loc2(const unsigned* __restrict__ cols,
                                              unsigned* parent1,
                                              unsigned short* __restrict__ closed,
                                              unsigned* __restrict__ parent2) {
    __shared__ unsigned sm[256];
    __shared__ unsigned su[2048];
    __shared__ unsigned sc[2048];
    int blk = blockIdx.x;
    int b = blk / (PHB * PWB), pr = blk % (PHB * PWB);
    int h0 = (pr / PWB) * PTH, w0 = (pr % PWB) * PTW;
    int t = threadIdx.x;
    int c = b * HW + (h0 + (t >> 5)) * W_ + (w0 + (t & 31));
    unsigned wk = cols[c] & 0xFFFFu;
    // hysteresis: keep weak runs whose component root is FLAGGED
    unsigned m = 0;
    {
        unsigned rem = wk; int idx = 0;
        while (rem) {
            int p = __ffs(rem) - 1;
            unsigned tt = rem >> p;
            int len = __ffs(~tt) - 1;
            unsigned runmask = ((1u << len) - 1u) << p;
            if (groot_val(parent1, (unsigned)idx * NCOL + c) == FLAGGED)
                m |= runmask;
            rem &= ~runmask; ++idx;
        }
    }
    // z-closing: dilate (OOB = background), erode (OOB = foreground)
    unsigned dil = (m | (m << 1) | (m >> 1)) & 0xFFFFu;
    unsigned ero = dil & ((dil << 1) | 1u) & ((dil >> 1) | 0x8000u);
    closed[c] = (unsigned short)ero;

    sm[t] = ero;
    #pragma unroll
    for (int i = 0; i < 8; ++i) { su[i * 256 + t] = i * 256 + t; sc[i * 256 + t] = 0; }
    __syncthreads();
    patch_unions(su, sm, ero, t);
    __syncthreads();
    // per-local-root voxel counts
    {
        unsigned rem = ero; int idx = 0;
        while (rem) {
            int p = __ffs(rem) - 1;
            unsigned tt = rem >> p;
            int len = __ffs(~tt) - 1;
            unsigned runmask = ((1u << len) - 1u) << p;
            atomicAdd(&sc[luf_find(su, (unsigned)idx * 256 + t)], (unsigned)len);
            rem &= ~runmask; ++idx;
        }
    }
    __syncthreads();
    int nr = nruns(ero);
    for (int i = 0; i < nr; ++i) {
        unsigned lid = (unsigned)i * 256 + t;
        unsigned lr  = luf_find(su, lid);
        unsigned gid = (unsigned)i * NCOL + c;
        if (lr == lid) parent2[gid] = 0xFFFFFFFFu - sc[lid];
        else {
            unsigned tt = lr & 255u, ss = lr >> 8;
            parent2[gid] = ss * NCOL +
                (unsigned)(b * HW + (h0 + (int)(tt >> 5)) * W_ + (w0 + (int)(tt & 31)));
        }
    }
}

// cross-patch boundary unions with count propagation (closed)
__global__ __launch_bounds__(256) void k_bnd2(const unsigned short* __restrict__ closed,
                                              unsigned* parent2) {
    int e = blockIdx.x * 256 + threadIdx.x;
    if (e >= NPAIRS) return;
    int b = e / PAIR_B, r = e % PAIR_B;
    int cA, cB;
    if (r < WPAIR_B) {
        int h = r / (PWB - 1), wi = r % (PWB - 1);
        cA = b * HW + h * W_ + wi * PTW + (PTW - 1);
        cB = cA + 1;
    } else {
        r -= WPAIR_B;
        int hi = r / W_, w = r % W_;
        cA = b * HW + (hi * PTH + (PTH - 1)) * W_ + w;
        cB = cA + W_;
    }
    unsigned mA = closed[cA];
    unsigned mB = closed[cB];
    unsigned ov = mA & mB;
    while (ov) {
        int p = __ffs(ov) - 1;
        gunite_cnt(parent2, (unsigned)runidx(mA, p) * NCOL + cA,
                            (unsigned)runidx(mB, p) * NCOL + cB);
        ov &= ov + (1u << p);
    }
}

// keep components with size >= DUST_MIN; write 0/1 float (4 cols/thread)
__global__ __launch_bounds__(256) void k_out(const unsigned short* __restrict__ closed,
                                             unsigned* parent2,
                                             float* __restrict__ out) {
    int q = blockIdx.x * 256 + threadIdx.x;
    int c0 = q * 4;
    int b = c0 / HW, off = c0 - b * HW;
    unsigned keep[4];
    #pragma unroll
    for (int j = 0; j < 4; ++j) {
        int c = c0 + j;
        unsigned fg = closed[c];
        unsigned k = 0;
        unsigned rem = fg; int idx = 0;
        while (rem) {
            int p = __ffs(rem) - 1;
            unsigned tt = rem >> p;
            int len = __ffs(~tt) - 1;
            unsigned runmask = ((1u << len) - 1u) << p;
            if (0xFFFFFFFFu - groot_val(parent2, (unsigned)idx * NCOL + c) >= DUST_MIN)
                k |= runmask;
            rem &= ~runmask; ++idx;
        }
        keep[j] = k;
    }
    float* op = out + (size_t)b * DHW + off;
    #pragma unroll
    for (int z = 0; z < D_; ++z) {
        *(float4*)(op + (size_t)z * HW) =
            make_float4((keep[0] >> z) & 1u ? 1.0f : 0.0f,
                        (keep[1] >> z) & 1u ? 1.0f : 0.0f,
                        (keep[2] >> z) & 1u ? 1.0f : 0.0f,
                        (keep[3] >> z) & 1u ? 1.0f : 0.0f);
    }
}

extern "C" void kernel_launch(void* const* d_in, const int* in_sizes, int n_in,
                              void* d_out, int out_size, void* d_ws, size_t ws_size,
                              hipStream_t stream) {
    const float* x = (const float*)d_in[0];
    float* out = (float*)d_out;

    // ws: parent1 [NRUN u32] | parent2 [NRUN u32] | cols [NCOL u32] | closed [NCOL u16]
    const size_t sz_parent = (size_t)NRUN * 4;
    const size_t sz_cols   = (size_t)NCOL * 4;
    const size_t sz_closed = (size_t)NCOL * 2;
    if (ws_size < 2 * sz_parent + sz_cols + sz_closed) return;
    char* ws = (char*)d_ws;
    unsigned*       parent1 = (unsigned*)ws;
    unsigned*       parent2 = (unsigned*)(ws + sz_parent);
    unsigned*       cols    = (unsigned*)(ws + 2 * sz_parent);
    unsigned short* closed  = (unsigned short*)(ws + 2 * sz_parent + sz_cols);

    dim3 blk(256);
    dim3 grdQ(NBLK_QUAD), grdL(NPATCH), grdB((NPAIRS + 255) / 256);

    // ---- phase 1: weak-run CCL with inline strong flags ----
    k_cols<<<grdQ, blk, 0, stream>>>(x, cols);
    k_loc1<<<grdL, blk, 0, stream>>>(cols, parent1);
    k_bnd1<<<grdB, blk, 0, stream>>>(cols, parent1);

    // ---- phase 2: hysteresis+closing, closed-run CCL with inline counts ----
    k_loc2<<<grdL, blk, 0, stream>>>(cols, parent1, closed, parent2);
    k_bnd2<<<grdB, blk, 0, stream>>>(closed, parent2);
    k_out<<<grdQ, blk, 0, stream>>>(closed, parent2, out);
}

// Round 9
// 258.513 us; speedup vs baseline: 2.3020x; 1.0777x over previous
//
#include <hip/hip_runtime.h>
#include <stdint.h>

// Fixed problem shape: outputs [8,16,384,384] fp32
#define B_ 8
#define D_ 16
#define H_ 384
#define W_ 384
constexpr int HW   = H_ * W_;     // 147456
constexpr int DHW  = D_ * HW;     // 2359296
constexpr int NCOL = B_ * HW;     // 1179648 columns
// Stratified run ids: id = run_idx * NCOL + column (runs concentrate in strata 0..2)
constexpr unsigned NRUN = (unsigned)NCOL * 8u;

constexpr float T_LOW  = 0.8f;
constexpr float T_HIGH = 0.92f;
constexpr unsigned DUST_MIN = 20u;
constexpr unsigned FLAGGED = 0xFFFFFFFEu;   // phase-1 root value: has strong voxel

constexpr int NBLK_QUAD = NCOL / 1024;  // 1152 (4 cols/thread kernels)

// local-UF patches (32x8 cols, 256 threads = 1 col/thread)
constexpr int PTW = 32, PTH = 8;
constexpr int PWB = W_ / PTW;             // 12
constexpr int PHB = H_ / PTH;             // 48
constexpr int NPATCH = B_ * PWB * PHB;    // 4608

// boundary column-pairs between patches
constexpr int WPAIR_B = (PWB - 1) * H_;      // 4224
constexpr int HPAIR_B = (PHB - 1) * W_;      // 18048
constexpr int PAIR_B  = WPAIR_B + HPAIR_B;   // 22272
constexpr int NPAIRS  = B_ * PAIR_B;         // 178176

// ---------- global union-find over stratified z-run ids ----------
// parent[] : value < NRUN -> parent pointer; value >= NRUN -> root encoding.
// Phase 1 roots: 0xFFFFFFFF = no strong, 0xFFFFFFFE = has strong.
// Phase 2 roots: 0xFFFFFFFF - componentVoxelCount.
// Parents only ever decrease; halving stores only past-ancestor pointers (safe).
__device__ __forceinline__ unsigned gfind(unsigned* A, unsigned x) {
    for (;;) {
        unsigned p = A[x];
        if (p >= NRUN) return x;
        unsigned g = A[p];
        if (g >= NRUN) return p;
        A[x] = g;
        x = g;
    }
}

__device__ __forceinline__ unsigned groot_val(unsigned* A, unsigned x) {
    for (;;) {
        unsigned p = A[x];
        if (p >= NRUN) return p;
        unsigned g = A[p];
        if (g >= NRUN) return g;
        A[x] = g;
        x = g;
    }
}

// ensure the root of x's component is flagged (phase 1)
__device__ __forceinline__ void set_flag(unsigned* A, unsigned x) {
    unsigned r = gfind(A, x);
    for (;;) {
        unsigned old = atomicMin(&A[r], FLAGGED);
        if (old >= NRUN) return;
        r = gfind(A, old);
    }
}

// add cnt into the root encoding of x's component (phase 2).
__device__ __forceinline__ void add_count(unsigned* A, unsigned x, unsigned cnt) {
    unsigned r = gfind(A, x);
    for (;;) {
        unsigned old = A[r];
        if (old < NRUN) { r = gfind(A, old); continue; }
        if (atomicCAS(&A[r], old, old - cnt) == old) return;
    }
}

// union with flag propagation (phase 1)
__device__ __forceinline__ void gunite_flag(unsigned* A, unsigned a, unsigned b) {
    for (;;) {
        a = gfind(A, a);
        b = gfind(A, b);
        if (a == b) return;
        unsigned lo = a < b ? a : b;
        unsigned hi = a < b ? b : a;
        unsigned old = atomicMin(&A[hi], lo);
        if (old >= NRUN) {
            if (old == FLAGGED) set_flag(A, lo);
            return;
        }
        a = lo; b = old;
    }
}

// union with count propagation (phase 2)
__device__ __forceinline__ void gunite_cnt(unsigned* A, unsigned a, unsigned b) {
    for (;;) {
        a = gfind(A, a);
        b = gfind(A, b);
        if (a == b) return;
        unsigned lo = a < b ? a : b;
        unsigned hi = a < b ? b : a;
        unsigned old = atomicMin(&A[hi], lo);
        if (old >= NRUN) {
            unsigned cnt = 0xFFFFFFFFu - old;
            if (cnt) add_count(A, lo, cnt);
            return;
        }
        a = lo; b = old;
    }
}

// run index containing set bit p of mask m
__device__ __forceinline__ int runidx(unsigned m, int p) {
    unsigned starts = m & ~(m << 1);
    return __popc(starts & ((2u << p) - 1u)) - 1;
}

__device__ __forceinline__ int nruns(unsigned m) {
    return __popc(m & ~(m << 1));
}

// ---------- patch-local LDS union-find (ids: run_idx*256 + thread) ----------
// path-halving: stores past-ancestor values only (monotone chains -> safe)
__device__ __forceinline__ unsigned luf_find(unsigned* su, unsigned x) {
    for (;;) {
        unsigned p = su[x];
        if (p == x) return x;
        unsigned g = su[p];
        if (g == p) return p;
        su[x] = g;
        x = g;
    }
}

__device__ __forceinline__ void luf_union(unsigned* su, unsigned a, unsigned b) {
    for (;;) {
        a = luf_find(su, a);
        b = luf_find(su, b);
        if (a == b) return;
        unsigned lo = a < b ? a : b;
        unsigned hi = a < b ? b : a;
        unsigned old = atomicMin(&su[hi], lo);
        if (old == hi) return;
        a = lo; b = old;
    }
}

// intra-patch unions for column t against neighbors t+1, t+32 (masks in sm)
__device__ __forceinline__ void patch_unions(unsigned* su, const unsigned* sm,
                                             unsigned m, int t) {
    int lw = t & 31, lh = t >> 5;
    if (!m) return;
    if (lw < 31) {
        unsigned mB = sm[t + 1];
        unsigned ov = m & mB;
        while (ov) {
            int p = __ffs(ov) - 1;
            luf_union(su, (unsigned)runidx(m, p) * 256 + t,
                          (unsigned)runidx(mB, p) * 256 + t + 1);
            ov &= ov + (1u << p);
        }
    }
    if (lh < 7) {
        unsigned mB = sm[t + 32];
        unsigned ov = m & mB;
        while (ov) {
            int p = __ffs(ov) - 1;
            luf_union(su, (unsigned)runidx(m, p) * 256 + t,
                          (unsigned)runidx(mB, p) * 256 + t + 32);
            ov &= ov + (1u << p);
        }
    }
}

// ---------------- kernels ----------------

// x -> thresholds in-reg -> patch-local UF on weak masks; roots carry strong
// flag; writes weak-mask array (u16) and all parent1 entries
__global__ __launch_bounds__(256) void k_loc1(const float* __restrict__ x,
                                              unsigned short* __restrict__ weakm,
                                              unsigned* __restrict__ parent1) {
    __shared__ unsigned sm[256];
    __shared__ unsigned su[2048];
    __shared__ unsigned sf[2048];
    int blk = blockIdx.x;
    int b = blk / (PHB * PWB), pr = blk % (PHB * PWB);
    int h0 = (pr / PWB) * PTH, w0 = (pr % PWB) * PTW;
    int t = threadIdx.x;
    int c = b * HW + (h0 + (t >> 5)) * W_ + (w0 + (t & 31));
    const float* xp = x + (size_t)b * DHW + (size_t)(h0 + (t >> 5)) * W_ + (w0 + (t & 31));
    float vz[16];
    #pragma unroll
    for (int z = 0; z < 16; ++z) vz[z] = xp[(size_t)z * HW];   // 16 independent loads
    unsigned m = 0, st = 0;
    #pragma unroll
    for (int z = 0; z < 16; ++z) {
        m  |= (vz[z] >= T_LOW  ? 1u : 0u) << z;
        st |= (vz[z] >= T_HIGH ? 1u : 0u) << z;
    }
    weakm[c] = (unsigned short)m;
    sm[t] = m;
    #pragma unroll
    for (int i = 0; i < 8; ++i) { su[i * 256 + t] = i * 256 + t; sf[i * 256 + t] = 0; }
    __syncthreads();
    patch_unions(su, sm, m, t);
    __syncthreads();
    if (st) {
        unsigned rem = m; int idx = 0;
        while (rem) {
            int p = __ffs(rem) - 1;
            unsigned tt = rem >> p;
            int len = __ffs(~tt) - 1;
            unsigned runmask = ((1u << len) - 1u) << p;
            if (runmask & st) sf[luf_find(su, (unsigned)idx * 256 + t)] = 1u;
            rem &= ~runmask; ++idx;
        }
    }
    __syncthreads();
    int nr = nruns(m);
    for (int i = 0; i < nr; ++i) {
        unsigned lid = (unsigned)i * 256 + t;
        unsigned lr  = luf_find(su, lid);
        unsigned gid = (unsigned)i * NCOL + c;
        if (lr == lid) parent1[gid] = sf[lid] ? FLAGGED : 0xFFFFFFFFu;
        else {
            unsigned tt = lr & 255u, ss = lr >> 8;
            parent1[gid] = ss * NCOL +
                (unsigned)(b * HW + (h0 + (int)(tt >> 5)) * W_ + (w0 + (int)(tt & 31)));
        }
    }
}

// cross-patch boundary unions with flag propagation (weak)
__global__ __launch_bounds__(256) void k_bnd1(const unsigned short* __restrict__ weakm,
                                              unsigned* parent1) {
    int e = blockIdx.x * 256 + threadIdx.x;
    if (e >= NPAIRS) return;
    int b = e / PAIR_B, r = e % PAIR_B;
    int cA, cB;
    if (r < WPAIR_B) {
        int h = r / (PWB - 1), wi = r % (PWB - 1);
        cA = b * HW + h * W_ + wi * PTW + (PTW - 1);
        cB = cA + 1;
    } else {
        r -= WPAIR_B;
        int hi = r / W_, w = r % W_;
        cA = b * HW + (hi * PTH + (PTH - 1)) * W_ + w;
        cB = cA + W_;
    }
    unsigned mA = weakm[cA];
    unsigned mB = weakm[cB];
    unsigned ov = mA & mB;
    while (ov) {
        int p = __ffs(ov) - 1;
        gunite_flag(parent1, (unsigned)runidx(mA, p) * NCOL + cA,
                             (unsigned)runidx(mB, p) * NCOL + cB);
        ov &= ov + (1u << p);
    }
}

// hysteresis (prefetched first-hop chase) + z-closing + patch-local UF on
// closed masks with per-local-root voxel counts; writes closed + parent2
__global__ __launch_bounds__(256) void k_loc2(const unsigned short* __restrict__ weakm,
                                              unsigned* parent1,
                                              unsigned short* __restrict__ closed,
                                              unsigned* __restrict__ parent2) {
    __shared__ unsigned sm[256];
    __shared__ unsigned su[2048];
    __shared__ unsigned sc[2048];
    int blk = blockIdx.x;
    int b = blk / (PHB * PWB), pr = blk % (PHB * PWB);
    int h0 = (pr / PWB) * PTH, w0 = (pr % PWB) * PTW;
    int t = threadIdx.x;
    int c = b * HW + (h0 + (t >> 5)) * W_ + (w0 + (t & 31));
    unsigned wk = weakm[c];
    int nrw = nruns(wk);
    // prefetch first hop for up to 4 runs (independent, predicated loads)
    unsigned pv[4];
    #pragma unroll
    for (int i = 0; i < 4; ++i) if (i < nrw) pv[i] = parent1[(unsigned)i * NCOL + c];
    unsigned m = 0;
    {
        unsigned rem = wk; int idx = 0;
        while (rem) {
            int p = __ffs(rem) - 1;
            unsigned tt = rem >> p;
            int len = __ffs(~tt) - 1;
            unsigned runmask = ((1u << len) - 1u) << p;
            unsigned rv;
            if (idx < 4) { unsigned v = pv[idx]; rv = (v >= NRUN) ? v : groot_val(parent1, v); }
            else rv = groot_val(parent1, (unsigned)idx * NCOL + c);
            if (rv == FLAGGED) m |= runmask;
            rem &= ~runmask; ++idx;
        }
    }
    // z-closing: dilate (OOB = background), erode (OOB = foreground)
    unsigned dil = (m | (m << 1) | (m >> 1)) & 0xFFFFu;
    unsigned ero = dil & ((dil << 1) | 1u) & ((dil >> 1) | 0x8000u);
    closed[c] = (unsigned short)ero;

    sm[t] = ero;
    #pragma unroll
    for (int i = 0; i < 8; ++i) { su[i * 256 + t] = i * 256 + t; sc[i * 256 + t] = 0; }
    __syncthreads();
    patch_unions(su, sm, ero, t);
    __syncthreads();
    {
        unsigned rem = ero; int idx = 0;
        while (rem) {
            int p = __ffs(rem) - 1;
            unsigned tt = rem >> p;
            int len = __ffs(~tt) - 1;
            unsigned runmask = ((1u << len) - 1u) << p;
            atomicAdd(&sc[luf_find(su, (unsigned)idx * 256 + t)], (unsigned)len);
            rem &= ~runmask; ++idx;
        }
    }
    __syncthreads();
    int nr = nruns(ero);
    for (int i = 0; i < nr; ++i) {
        unsigned lid = (unsigned)i * 256 + t;
        unsigned lr  = luf_find(su, lid);
        unsigned gid = (unsigned)i * NCOL + c;
        if (lr == lid) parent2[gid] = 0xFFFFFFFFu - sc[lid];
        else {
            unsigned tt = lr & 255u, ss = lr >> 8;
            parent2[gid] = ss * NCOL +
                (unsigned)(b * HW + (h0 + (int)(tt >> 5)) * W_ + (w0 + (int)(tt & 31)));
        }
    }
}

// cross-patch boundary unions with count propagation (closed)
__global__ __launch_bounds__(256) void k_bnd2(const unsigned short* __restrict__ closed,
                                              unsigned* parent2) {
    int e = blockIdx.x * 256 + threadIdx.x;
    if (e >= NPAIRS) return;
    int b = e / PAIR_B, r = e % PAIR_B;
    int cA, cB;
    if (r < WPAIR_B) {
        int h = r / (PWB - 1), wi = r % (PWB - 1);
        cA = b * HW + h * W_ + wi * PTW + (PTW - 1);
        cB = cA + 1;
    } else {
        r -= WPAIR_B;
        int hi = r / W_, w = r % W_;
        cA = b * HW + (hi * PTH + (PTH - 1)) * W_ + w;
        cB = cA + W_;
    }
    unsigned mA = closed[cA];
    unsigned mB = closed[cB];
    unsigned ov = mA & mB;
    while (ov) {
        int p = __ffs(ov) - 1;
        gunite_cnt(parent2, (unsigned)runidx(mA, p) * NCOL + cA,
                            (unsigned)runidx(mB, p) * NCOL + cB);
        ov &= ov + (1u << p);
    }
}

// keep components with size >= DUST_MIN; write 0/1 float (4 cols/thread)
__global__ __launch_bounds__(256) void k_out(const unsigned short* __restrict__ closed,
                                             unsigned* parent2,
                                             float* __restrict__ out) {
    int q = blockIdx.x * 256 + threadIdx.x;
    int c0 = q * 4;
    int b = c0 / HW, off = c0 - b * HW;
    ushort4 cc4 = *(const ushort4*)(closed + c0);
    unsigned fg[4] = {cc4.x, cc4.y, cc4.z, cc4.w};
    // prefetch first hop for up to 4 runs per column (16 independent loads)
    unsigned pv[4][4];
    int nr[4];
    #pragma unroll
    for (int j = 0; j < 4; ++j) {
        nr[j] = nruns(fg[j]);
        #pragma unroll
        for (int i = 0; i < 4; ++i)
            if (i < nr[j]) pv[j][i] = parent2[(unsigned)i * NCOL + (c0 + j)];
    }
    unsigned keep[4];
    #pragma unroll
    for (int j = 0; j < 4; ++j) {
        int c = c0 + j;
        unsigned k = 0;
        unsigned rem = fg[j]; int idx = 0;
        while (rem) {
            int p = __ffs(rem) - 1;
            unsigned tt = rem >> p;
            int len = __ffs(~tt) - 1;
            unsigned runmask = ((1u << len) - 1u) << p;
            unsigned rv;
            if (idx < 4) { unsigned v = pv[j][idx]; rv = (v >= NRUN) ? v : groot_val(parent2, v); }
            else rv = groot_val(parent2, (unsigned)idx * NCOL + c);
            if (0xFFFFFFFFu - rv >= DUST_MIN) k |= runmask;
            rem &= ~runmask; ++idx;
        }
        keep[j] = k;
    }
    float* op = out + (size_t)b * DHW + off;
    #pragma unroll
    for (int z = 0; z < D_; ++z) {
        *(float4*)(op + (size_t)z * HW) =
            make_float4((keep[0] >> z) & 1u ? 1.0f : 0.0f,
                        (keep[1] >> z) & 1u ? 1.0f : 0.0f,
                        (keep[2] >> z) & 1u ? 1.0f : 0.0f,
                        (keep[3] >> z) & 1u ? 1.0f : 0.0f);
    }
}

extern "C" void kernel_launch(void* const* d_in, const int* in_sizes, int n_in,
                              void* d_out, int out_size, void* d_ws, size_t ws_size,
                              hipStream_t stream) {
    const float* x = (const float*)d_in[0];
    float* out = (float*)d_out;

    // ws: parent1 [NRUN u32] | parent2 [NRUN u32] | weak [NCOL u16] | closed [NCOL u16]
    const size_t sz_parent = (size_t)NRUN * 4;
    const size_t sz_mask   = (size_t)NCOL * 2;
    if (ws_size < 2 * sz_parent + 2 * sz_mask) return;
    char* ws = (char*)d_ws;
    unsigned*       parent1 = (unsigned*)ws;
    unsigned*       parent2 = (unsigned*)(ws + sz_parent);
    unsigned short* weakm   = (unsigned short*)(ws + 2 * sz_parent);
    unsigned short* closed  = (unsigned short*)(ws + 2 * sz_parent + sz_mask);

    dim3 blk(256);
    dim3 grdL(NPATCH), grdB((NPAIRS + 255) / 256), grdQ(NBLK_QUAD);

    // ---- phase 1: weak-run CCL with inline strong flags ----
    k_loc1<<<grdL, blk, 0, stream>>>(x, weakm, parent1);
    k_bnd1<<<grdB, blk, 0, stream>>>(weakm, parent1);

    // ---- phase 2: hysteresis+closing, closed-run CCL with inline counts ----
    k_loc2<<<grdL, blk, 0, stream>>>(weakm, parent1, closed, parent2);
    k_bnd2<<<grdB, blk, 0, stream>>>(closed, parent2);
    k_out<<<grdQ, blk, 0, stream>>>(closed, parent2, out);
}